// Round 1
// baseline (7441.608 us; speedup 1.0000x reference)
//
#include <hip/hip_runtime.h>
#include <stdint.h>

typedef unsigned long long u64;

#define NN 2048      // problem size
#define NW 32        // u64 words per 2048-bit row mask

// ---------------------------------------------------------------------------
// Kernel A: per-row precompute.
//  - he bitmask: he[i][j] = (logsig(e)+g0 > logsig(-e)+g1), packed 64/word
//  - zero the dag output row (harness poisons d_out)
//  - anc[i] = {i} (eye init)
// ---------------------------------------------------------------------------
__global__ __launch_bounds__(256) void prep_kernel(
    const float* __restrict__ edge_logits,
    const float* __restrict__ g_edge,
    float* __restrict__ dag,
    u64* __restrict__ heBits,
    u64* __restrict__ anc)
{
    const int i    = blockIdx.x;
    const int t    = threadIdx.x;
    const int lane = t & 63;
    const int wave = t >> 6;   // 4 waves

    for (int c = wave; c < NW; c += 4) {
        int j = (c << 6) + lane;
        float x  = edge_logits[i * NN + j];
        float g0 = g_edge[(size_t)i * (2 * NN) + j];
        float g1 = g_edge[(size_t)i * (2 * NN) + NN + j];
        // match jax.nn.log_sigmoid(x) = -(max(-x,0) + log1p(exp(-|x|)))
        float L = log1pf(expf(-fabsf(x)));
        float a = (-(fmaxf(-x, 0.f) + L)) + g0;   // ye[i][0][j]
        float b = (-(fmaxf( x, 0.f) + L)) + g1;   // ye[i][1][j]
        u64 m = __ballot(a > b);
        if (lane == 0) heBits[i * NW + c] = m;
    }
    // zero output row
    for (int k = t; k < NN; k += 256) dag[(size_t)i * NN + k] = 0.f;
    // anc row = self bit (anc0 = eye)
    if (t < NW) anc[i * NW + t] = (t == (i >> 6)) ? (1ull << (i & 63)) : 0ull;
}

// ---------------------------------------------------------------------------
// Kernel B: sequential BFS, one workgroup of 1024 threads.
// Queue / enq / popped / root masks live in LDS; he / anc bitsets in global ws.
// ---------------------------------------------------------------------------
__global__ __launch_bounds__(1024) void bfs_kernel(
    const float* __restrict__ root_logits,
    const float* __restrict__ g_root,
    const u64* __restrict__ heBits,
    u64* __restrict__ anc,
    float* __restrict__ dag)
{
    __shared__ u64 s_root[NW];
    __shared__ u64 s_enq[NW];
    __shared__ u64 s_popped[NW];
    __shared__ u64 s_anc[NW];
    __shared__ u64 s_he[NW];
    __shared__ u64 s_cm[NW];     // children mask = he & ~anc_i & ~root
    __shared__ u64 s_new[NW];    // cm & ~enq  (queue appends)
    __shared__ u64 s_pm[NW];     // cm & ~popped (push targets)
    __shared__ int s_queue[NN];
    __shared__ unsigned short s_clist[NN];
    __shared__ int s_cbase[NW + 1];
    __shared__ int s_qbase[NW + 1];
    __shared__ int s_head, s_tail, s_i, s_nw, s_wz;

    const int t    = threadIdx.x;
    const int lane = t & 63;

    // ---- root bits (2 passes of 1024 lanes, ballot-packed) ----
    for (int p = 0; p < 2; ++p) {
        int j = p * 1024 + t;
        float x  = root_logits[j];
        float g0 = g_root[j];
        float g1 = g_root[NN + j];
        float L = log1pf(expf(-fabsf(x)));
        float a = (-(fmaxf(-x, 0.f) + L)) + g0;
        float b = (-(fmaxf( x, 0.f) + L)) + g1;
        u64 m = __ballot(a > b);
        if (lane == 0) s_root[j >> 6] = m;
    }
    if (t < NW) s_popped[t] = 0ull;
    __syncthreads();
    if (t < NW) s_enq[t] = s_root[t];
    // queue init: roots in ascending index order (prefix popcount)
    for (int p = 0; p < 2; ++p) {
        int j = p * 1024 + t;
        int w = j >> 6;
        u64 bit = 1ull << (j & 63);
        if (s_root[w] & bit) {
            int pos = 0;
            for (int k = 0; k < w; ++k) pos += __popcll(s_root[k]);
            pos += __popcll(s_root[w] & (bit - 1));
            s_queue[pos] = j;
        }
    }
    if (t == 0) {
        int tl = 0;
        for (int k = 0; k < NW; ++k) tl += __popcll(s_root[k]);
        s_tail = tl;
        s_head = 0;
    }
    __syncthreads();

    // ---- BFS pop loop ----
    while (true) {
        if (s_head >= s_tail) break;           // uniform
        if (t == 0) s_i = s_queue[s_head];
        __syncthreads();                        // P0
        const int i = s_i;

        // P1: load he row + anc row (32 u64 each)
        if (t < NW)            s_he[t]       = heBits[i * NW + t];
        else if (t < 2 * NW)   s_anc[t - NW] = anc[i * NW + (t - NW)];
        __syncthreads();

        // P2: word-wise masks
        if (t < NW) {
            u64 cm  = s_he[t] & ~s_anc[t] & ~s_root[t];
            s_cm[t]  = cm;
            s_new[t] = cm & ~s_enq[t];
            s_pm[t]  = cm & ~s_popped[t];
        }
        __syncthreads();

        // P3: serial prefix scans (3 independent threads) + dag row write (all)
        if (t == 0) {
            int acc = 0;
            for (int w = 0; w < NW; ++w) { s_cbase[w] = acc; acc += __popcll(s_pm[w]); }
            s_cbase[NW] = acc;
        } else if (t == 64) {
            int acc = 0;
            for (int w = 0; w < NW; ++w) { s_qbase[w] = acc; acc += __popcll(s_new[w]); }
            s_qbase[NW] = acc;
        } else if (t == 128) {
            int nz = 0, wz = 0;
            for (int w = 0; w < NW; ++w) if (s_anc[w]) { nz++; wz = w; }
            s_nw = nz; s_wz = wz;
        }
        {   // dag[i] row: 1.0f where cm bit set (row pre-zeroed by prep)
            for (int p = 0; p < 2; ++p) {
                int j = p * 1024 + t;
                if ((s_cm[j >> 6] >> (j & 63)) & 1ull) dag[(size_t)i * NN + j] = 1.0f;
            }
        }
        __syncthreads();

        // P4: enumerate push-target list; append new children to queue (asc order)
        if (t < NW) {
            u64 m = s_pm[t];
            int base = s_cbase[t];
            int wb = t << 6;
            while (m) { int b = __ffsll(m) - 1; s_clist[base++] = (unsigned short)(wb + b); m &= m - 1; }
        } else if (t >= 64 && t < 64 + NW) {
            int w = t - 64;
            u64 m = s_new[w];
            int base = s_tail + s_qbase[w];
            int wb = w << 6;
            while (m) { int b = __ffsll(m) - 1; s_queue[base++] = wb + b; m &= m - 1; }
        }
        if (t < NW) s_enq[t] |= s_new[t];
        __syncthreads();

        // P5: push anc_i into children; bookkeeping
        const int nC = s_cbase[NW];
        if (s_nw <= 1) {
            // root-ish fast path: single nonzero anc word
            const int wz = s_wz;
            const u64 v = s_anc[wz];
            for (int k = t; k < nC; k += 1024) {
                int c = s_clist[k];
                anc[c * NW + wz] |= v;
            }
        } else {
            for (int k = t; k < nC * NW; k += 1024) {
                int c = s_clist[k >> 5];
                int w = k & 31;
                u64 v = s_anc[w];
                if (v) anc[c * NW + w] |= v;
            }
        }
        if (t == 0) {
            s_tail += s_qbase[NW];
            s_head += 1;
            s_popped[i >> 6] |= 1ull << (i & 63);
        }
        __syncthreads();
    }
}

// ---------------------------------------------------------------------------
extern "C" void kernel_launch(void* const* d_in, const int* in_sizes, int n_in,
                              void* d_out, int out_size, void* d_ws, size_t ws_size,
                              hipStream_t stream) {
    const float* root_logits = (const float*)d_in[0];
    const float* edge_logits = (const float*)d_in[1];
    const float* g_root      = (const float*)d_in[2];
    const float* g_edge      = (const float*)d_in[3];
    float* dag = (float*)d_out;

    // ws layout: heBits (512 KB) | anc (512 KB)
    u64* heBits = (u64*)d_ws;
    u64* anc    = (u64*)((char*)d_ws + (size_t)NN * NW * sizeof(u64));

    prep_kernel<<<NN, 256, 0, stream>>>(edge_logits, g_edge, dag, heBits, anc);
    bfs_kernel<<<1, 1024, 0, stream>>>(root_logits, g_root, heBits, anc, dag);
}

// Round 2
// 786.364 us; speedup vs baseline: 9.4633x; 9.4633x over previous
//
#include <hip/hip_runtime.h>
#include <stdint.h>

typedef unsigned long long u64;

#define NN 2048
#define NW 32    // u64 words per 2048-bit row

static __device__ __forceinline__ bool gumbel_gt(float x, float g0, float g1) {
    // jax.nn.log_sigmoid(x) = -(max(-x,0) + log1p(exp(-|x|)))
    float L = log1pf(expf(-fabsf(x)));
    float a = (-(fmaxf(-x, 0.f) + L)) + g0;   // ye[0]
    float b = (-(fmaxf( x, 0.f) + L)) + g1;   // ye[1]
    return a > b;
}

// ---------------------------------------------------------------------------
// K1: hard-edge bitmask  he[i][j] = (logsig(e)+g0 > logsig(-e)+g1)
// ---------------------------------------------------------------------------
__global__ __launch_bounds__(256) void prep_kernel(
    const float* __restrict__ edge_logits,
    const float* __restrict__ g_edge,
    u64* __restrict__ heBits)
{
    const int i = blockIdx.x;
    const int t = threadIdx.x;
    const int lane = t & 63;
    const int wave = t >> 6;
    for (int c = wave; c < NW; c += 4) {
        int j = (c << 6) + lane;
        float x  = edge_logits[(size_t)i * NN + j];
        float g0 = g_edge[(size_t)i * (2 * NN) + j];
        float g1 = g_edge[(size_t)i * (2 * NN) + NN + j];
        u64 m = __ballot(gumbel_gt(x, g0, g1));
        if (lane == 0) heBits[(size_t)i * NW + c] = m;
    }
}

// ---------------------------------------------------------------------------
// K2: level-synchronous BFS order. One block, 1024 threads.
// Produces pos[] (pop rank, INF if unreached), rootM, reachM.
// Within a level, order = (rank of first parent in previous level, node index).
// ---------------------------------------------------------------------------
__global__ __launch_bounds__(1024) void order_kernel(
    const float* __restrict__ root_logits,
    const float* __restrict__ g_root,
    const u64* __restrict__ heBits,
    u64* __restrict__ rootM,
    u64* __restrict__ reachM,
    int* __restrict__ pos)
{
    __shared__ u64 s_root[NW], s_enq[NW], s_F[NW];
    __shared__ u64 s_part[32][NW];
    __shared__ int s_porder[NN];
    __shared__ unsigned short s_f[NN];
    __shared__ int s_cnt[NN];
    __shared__ int s_wsum[16], s_woff[16];
    __shared__ int s_base, s_lo, s_levcnt, s_newcnt;

    const int t = threadIdx.x;
    const int lane = t & 63;
    const int wid = t >> 6;

    // root bits
    for (int p = 0; p < 2; ++p) {
        int j = p * 1024 + t;
        bool rb = gumbel_gt(root_logits[j], g_root[j], g_root[NN + j]);
        u64 m = __ballot(rb);
        if (lane == 0) s_root[j >> 6] = m;
    }
    __syncthreads();
    // level 0 = roots ascending; pos init
    for (int p = 0; p < 2; ++p) {
        int j = p * 1024 + t;
        int w = j >> 6; u64 bit = 1ull << (j & 63);
        int pp = 0x7fffffff;
        if (s_root[w] & bit) {
            int r = 0;
            for (int k = 0; k < w; ++k) r += __popcll(s_root[k]);
            r += __popcll(s_root[w] & (bit - 1ull));
            pp = r;
            s_porder[r] = j;
        }
        pos[j] = pp;
    }
    if (t < NW) s_enq[t] = s_root[t];
    if (t == 0) {
        int tl = 0;
        for (int k = 0; k < NW; ++k) tl += __popcll(s_root[k]);
        s_lo = 0; s_levcnt = tl; s_base = tl;
    }
    __syncthreads();

    while (s_levcnt > 0 && s_base < NN) {
        const int lo = s_lo, cnt = s_levcnt, base = s_base;
        // frontier = OR of he rows of level members
        {
            int g = t >> 5, w = t & 31;
            u64 acc = 0;
            for (int m = g; m < cnt; m += 32)
                acc |= heBits[(size_t)s_porder[lo + m] * NW + w];
            s_part[g][w] = acc;
        }
        __syncthreads();
        if (t < NW) {
            u64 acc = 0;
            #pragma unroll
            for (int g = 0; g < 32; ++g) acc |= s_part[g][t];
            s_F[t] = acc & ~s_enq[t] & ~s_root[t];
        }
        for (int m = t; m < cnt; m += 1024) s_cnt[m] = 0;
        __syncthreads();
        // first-parent rank within previous level + bucket counts
        for (int p = 0; p < 2; ++p) {
            int j = p * 1024 + t;
            int w = j >> 6;
            if ((s_F[w] >> (j & 63)) & 1ull) {
                u64 jb = 1ull << (j & 63);
                int f = 0;
                for (; f < cnt; ++f) {
                    int par = s_porder[lo + f];
                    if (heBits[(size_t)par * NW + w] & jb) break;
                }
                if (f >= cnt) f = cnt - 1;   // unreachable by construction
                s_f[j] = (unsigned short)f;
                atomicAdd(&s_cnt[f], 1);
            }
        }
        __syncthreads();
        // exclusive prefix over s_cnt[0..cnt): 2 elems/thread + shuffle scans
        {
            int b0 = 2 * t, b1 = 2 * t + 1;
            int c0 = (b0 < cnt) ? s_cnt[b0] : 0;
            int c1 = (b1 < cnt) ? s_cnt[b1] : 0;
            int pairv = c0 + c1;
            int incl = pairv;
            for (int d = 1; d < 64; d <<= 1) {
                int v = __shfl_up(incl, d, 64);
                if (lane >= d) incl += v;
            }
            if (lane == 63) s_wsum[wid] = incl;
            __syncthreads();
            if (t < 16) {
                int v = s_wsum[t];
                int inc2 = v;
                for (int d = 1; d < 16; d <<= 1) {
                    int u = __shfl_up(inc2, d, 16);
                    if (t >= d) inc2 += u;
                }
                s_woff[t] = inc2 - v;
                if (t == 15) s_newcnt = inc2;
            }
            __syncthreads();
            int excl = s_woff[wid] + (incl - pairv);
            if (b0 < cnt) s_cnt[b0] = excl;
            if (b1 < cnt) s_cnt[b1] = excl + c0;
        }
        __syncthreads();
        // stable within-bucket rank (by ascending j) + scatter
        for (int p = 0; p < 2; ++p) {
            int j = p * 1024 + t;
            int w = j >> 6;
            if ((s_F[w] >> (j & 63)) & 1ull) {
                int f = s_f[j];
                int r = 0;
                for (int w2 = 0; w2 <= w; ++w2) {
                    u64 m = s_F[w2];
                    if (w2 == w) m &= (1ull << (j & 63)) - 1ull;
                    while (m) {
                        int b = __ffsll(m) - 1;
                        m &= m - 1;
                        if (s_f[(w2 << 6) + b] == (unsigned short)f) ++r;
                    }
                }
                int slot = base + s_cnt[f] + r;
                pos[j] = slot;
                s_porder[slot] = j;
            }
        }
        if (t < NW) s_enq[t] |= s_F[t];
        __syncthreads();
        if (t == 0) { s_lo = base; s_levcnt = s_newcnt; s_base = base + s_newcnt; }
        __syncthreads();
    }
    if (t < NW) { rootM[t] = s_root[t]; reachM[t] = s_enq[t]; }
}

// ---------------------------------------------------------------------------
// K3: base matrix M0[i] = {E-parents of i} | {i} | rootM   (ancestor rows)
//     E[j->i] = he[j][i] & !root[i] & reach(j) & reach(i) & pos[j]<pos[i]
//     unreached i -> all-ones row (forces dag row to 0)
// ---------------------------------------------------------------------------
__global__ __launch_bounds__(256) void ebuild_kernel(
    const u64* __restrict__ heBits,
    const u64* __restrict__ rootM,
    const u64* __restrict__ reachM,
    const int* __restrict__ pos,
    u64* __restrict__ M0)
{
    const int i = blockIdx.x;
    const int t = threadIdx.x;
    const int lane = t & 63;
    const int wave = t >> 6;
    __shared__ int s_posi, s_fl;
    if (t == 0) {
        int fl = 0;
        if ((reachM[i >> 6] >> (i & 63)) & 1ull) fl |= 1;
        if ((rootM[i >> 6]  >> (i & 63)) & 1ull) fl |= 2;
        s_fl = fl; s_posi = pos[i];
    }
    __syncthreads();
    const int posi = s_posi;
    const bool reach_i = (s_fl & 1) != 0;
    const bool root_i  = (s_fl & 2) != 0;
    const int iw = i >> 6;
    const u64 ibit = 1ull << (i & 63);
    for (int w = wave; w < NW; w += 4) {
        int j = (w << 6) + lane;
        bool b = false;
        if (reach_i && !root_i) {
            b = ((heBits[(size_t)j * NW + iw] & ibit) != 0)
                && (((reachM[w] >> lane) & 1ull) != 0)
                && (pos[j] < posi);
        }
        u64 m = __ballot(b);
        if (lane == 0) {
            m |= rootM[w];
            if (w == iw) m |= ibit;
            if (!reach_i) m = ~0ull;
            M0[(size_t)i * NW + w] = m;
        }
    }
}

// ---------------------------------------------------------------------------
// K4: boolean squaring  B[i] = U_{k in A[i]} A[k]   (A reflexive => B >= A)
// Block covers 16 rows x 16-word half; k staged in 128-row LDS chunks.
// ---------------------------------------------------------------------------
#define SQ_CH 128
__global__ __launch_bounds__(256) void square_kernel(
    const u64* __restrict__ A, u64* __restrict__ Bo)
{
    __shared__ u64 S[SQ_CH][16];   // 16 KB
    __shared__ u64 RB[16][NW];     //  4 KB (own rows, full width for the k-bits)
    const int t  = threadIdx.x;
    const int rg = blockIdx.x >> 1;
    const int wh = blockIdx.x & 1;
    const int r0 = rg * 16;
    const int w0 = wh * 16;
    const int wl = t & 15;
    const int tr = t >> 4;

    for (int q = t; q < 16 * NW; q += 256)
        RB[q >> 5][q & 31] = A[(size_t)(r0 + (q >> 5)) * NW + (q & 31)];
    __syncthreads();
    u64 acc = RB[tr][w0 + wl];

    for (int c = 0; c < NN; c += SQ_CH) {
        __syncthreads();
        for (int q = t; q < SQ_CH * 16; q += 256)
            S[q >> 4][q & 15] = A[(size_t)(c + (q >> 4)) * NW + w0 + (q & 15)];
        __syncthreads();
        for (int kk = 0; kk < SQ_CH; kk += 64) {
            u64 rb = RB[tr][(c + kk) >> 6];
            #pragma unroll
            for (int k2 = 0; k2 < 64; ++k2) {
                u64 msk = 0ull - ((rb >> k2) & 1ull);
                acc |= S[kk + k2][wl] & msk;
            }
        }
    }
    Bo[(size_t)(r0 + tr) * NW + w0 + wl] = acc;
}

// ---------------------------------------------------------------------------
// K5: dag[i][j] = he[i][j] & ~R[i][j]  (root/self/reach all folded into R)
// ---------------------------------------------------------------------------
__global__ __launch_bounds__(256) void out_kernel(
    const u64* __restrict__ heBits,
    const u64* __restrict__ R,
    float* __restrict__ dag)
{
    const int i = blockIdx.x;
    const int t = threadIdx.x;
    __shared__ u64 s_valid[NW];
    if (t < NW)
        s_valid[t] = heBits[(size_t)i * NW + t] & ~R[(size_t)i * NW + t];
    __syncthreads();
    int j0 = t * 8;
    u64 v = s_valid[j0 >> 6];
    int sh = j0 & 63;
    float4 f0, f1;
    f0.x = ((v >> (sh + 0)) & 1ull) ? 1.f : 0.f;
    f0.y = ((v >> (sh + 1)) & 1ull) ? 1.f : 0.f;
    f0.z = ((v >> (sh + 2)) & 1ull) ? 1.f : 0.f;
    f0.w = ((v >> (sh + 3)) & 1ull) ? 1.f : 0.f;
    f1.x = ((v >> (sh + 4)) & 1ull) ? 1.f : 0.f;
    f1.y = ((v >> (sh + 5)) & 1ull) ? 1.f : 0.f;
    f1.z = ((v >> (sh + 6)) & 1ull) ? 1.f : 0.f;
    f1.w = ((v >> (sh + 7)) & 1ull) ? 1.f : 0.f;
    float4* o = (float4*)(dag + (size_t)i * NN + j0);
    o[0] = f0; o[1] = f1;
}

// ---------------------------------------------------------------------------
extern "C" void kernel_launch(void* const* d_in, const int* in_sizes, int n_in,
                              void* d_out, int out_size, void* d_ws, size_t ws_size,
                              hipStream_t stream) {
    const float* root_logits = (const float*)d_in[0];
    const float* edge_logits = (const float*)d_in[1];
    const float* g_root      = (const float*)d_in[2];
    const float* g_edge      = (const float*)d_in[3];
    float* dag = (float*)d_out;

    // ws (1 MB, same footprint as the passing round-1 kernel):
    u64* heBits = (u64*)d_ws;                                   // 512 KB
    u64* RB_    = (u64*)((char*)d_ws + (512 << 10));            // 512 KB (final R)
    // dead d_out regions as scratch (out_kernel rewrites everything last):
    u64* RA_    = (u64*)((char*)d_out + (1 << 20));             // 512 KB ping buffer
    int* pos    = (int*)((char*)d_out + (1 << 20) + (512 << 10));   // 8 KB
    u64* rootM  = (u64*)((char*)d_out + (1 << 20) + (520 << 10));   // 256 B
    u64* reachM = (u64*)((char*)d_out + (1 << 20) + (520 << 10) + 256); // 256 B

    prep_kernel <<<NN, 256, 0, stream>>>(edge_logits, g_edge, heBits);
    order_kernel<<<1, 1024, 0, stream>>>(root_logits, g_root, heBits, rootM, reachM, pos);
    ebuild_kernel<<<NN, 256, 0, stream>>>(heBits, rootM, reachM, pos, RA_);

    u64* a = RA_; u64* b = RB_;
    for (int s = 0; s < 11; ++s) {           // 2^11 >= max path length (2047)
        square_kernel<<<2 * (NN / 16), 256, 0, stream>>>(a, b);
        u64* tmp = a; a = b; b = tmp;
    }
    // 11 iterations: final result lands in RB_ (== a after the last swap)
    out_kernel<<<NN, 256, 0, stream>>>(heBits, a, dag);
}

// Round 3
// 337.504 us; speedup vs baseline: 22.0490x; 2.3299x over previous
//
#include <hip/hip_runtime.h>
#include <stdint.h>

typedef unsigned long long u64;
typedef unsigned short u16;

#define NN 2048
#define NW 32    // u64 words per 2048-bit row

static __device__ __forceinline__ bool gumbel_gt(float x, float g0, float g1) {
    // jax.nn.log_sigmoid(x) = -(max(-x,0) + log1p(exp(-|x|)))
    float L = log1pf(expf(-fabsf(x)));
    float a = (-(fmaxf(-x, 0.f) + L)) + g0;   // ye[0]
    float b = (-(fmaxf( x, 0.f) + L)) + g1;   // ye[1]
    return a > b;
}

// ---------------------------------------------------------------------------
// K1: hard-edge bitmask  he[i][j]
// ---------------------------------------------------------------------------
__global__ __launch_bounds__(256) void prep_kernel(
    const float* __restrict__ edge_logits,
    const float* __restrict__ g_edge,
    u64* __restrict__ heBits)
{
    const int i = blockIdx.x;
    const int t = threadIdx.x;
    const int lane = t & 63;
    const int wave = t >> 6;
    for (int c = wave; c < NW; c += 4) {
        int j = (c << 6) + lane;
        float x  = edge_logits[(size_t)i * NN + j];
        float g0 = g_edge[(size_t)i * (2 * NN) + j];
        float g1 = g_edge[(size_t)i * (2 * NN) + NN + j];
        u64 m = __ballot(gumbel_gt(x, g0, g1));
        if (lane == 0) heBits[(size_t)i * NW + c] = m;
    }
}

// ---------------------------------------------------------------------------
// K2: level-synchronous BFS order (proven core from round 2).
// Finale now assigns padding ranks to unreached nodes and emits:
//   posr[j] = pos | root<<15 | reach<<14   (u16)
//   porderW[b] = node with rank b          (u16)
//   nr = number of roots
// ---------------------------------------------------------------------------
__global__ __launch_bounds__(1024) void order_kernel(
    const float* __restrict__ root_logits,
    const float* __restrict__ g_root,
    const u64* __restrict__ heBits,
    u16* __restrict__ posr,
    u16* __restrict__ porderW,
    int* __restrict__ nrPtr)
{
    __shared__ u64 s_root[NW], s_enq[NW], s_F[NW];
    __shared__ u64 s_part[32][NW];
    __shared__ int s_porder[NN];
    __shared__ u16 s_pos[NN];
    __shared__ unsigned short s_f[NN];
    __shared__ int s_cnt[NN];
    __shared__ int s_wsum[16], s_woff[16];
    __shared__ int s_base, s_lo, s_levcnt, s_newcnt, s_nr;

    const int t = threadIdx.x;
    const int lane = t & 63;
    const int wid = t >> 6;

    // root bits
    for (int p = 0; p < 2; ++p) {
        int j = p * 1024 + t;
        bool rb = gumbel_gt(root_logits[j], g_root[j], g_root[NN + j]);
        u64 m = __ballot(rb);
        if (lane == 0) s_root[j >> 6] = m;
    }
    __syncthreads();
    // level 0 = roots ascending
    for (int p = 0; p < 2; ++p) {
        int j = p * 1024 + t;
        int w = j >> 6; u64 bit = 1ull << (j & 63);
        if (s_root[w] & bit) {
            int r = 0;
            for (int k = 0; k < w; ++k) r += __popcll(s_root[k]);
            r += __popcll(s_root[w] & (bit - 1ull));
            s_pos[j] = (u16)r;
            s_porder[r] = j;
        }
    }
    if (t < NW) s_enq[t] = s_root[t];
    if (t == 0) {
        int tl = 0;
        for (int k = 0; k < NW; ++k) tl += __popcll(s_root[k]);
        s_lo = 0; s_levcnt = tl; s_base = tl; s_nr = tl;
    }
    __syncthreads();

    while (s_levcnt > 0 && s_base < NN) {
        const int lo = s_lo, cnt = s_levcnt, base = s_base;
        // frontier = OR of he rows of level members
        {
            int g = t >> 5, w = t & 31;
            u64 acc = 0;
            for (int m = g; m < cnt; m += 32)
                acc |= heBits[(size_t)s_porder[lo + m] * NW + w];
            s_part[g][w] = acc;
        }
        __syncthreads();
        if (t < NW) {
            u64 acc = 0;
            #pragma unroll
            for (int g = 0; g < 32; ++g) acc |= s_part[g][t];
            s_F[t] = acc & ~s_enq[t] & ~s_root[t];
        }
        for (int m = t; m < cnt; m += 1024) s_cnt[m] = 0;
        __syncthreads();
        // first-parent rank within previous level + bucket counts
        for (int p = 0; p < 2; ++p) {
            int j = p * 1024 + t;
            int w = j >> 6;
            if ((s_F[w] >> (j & 63)) & 1ull) {
                u64 jb = 1ull << (j & 63);
                int f = 0;
                for (; f < cnt; ++f) {
                    int par = s_porder[lo + f];
                    if (heBits[(size_t)par * NW + w] & jb) break;
                }
                if (f >= cnt) f = cnt - 1;
                s_f[j] = (unsigned short)f;
                atomicAdd(&s_cnt[f], 1);
            }
        }
        __syncthreads();
        // exclusive prefix over s_cnt[0..cnt)
        {
            int b0 = 2 * t, b1 = 2 * t + 1;
            int c0 = (b0 < cnt) ? s_cnt[b0] : 0;
            int c1 = (b1 < cnt) ? s_cnt[b1] : 0;
            int pairv = c0 + c1;
            int incl = pairv;
            for (int d = 1; d < 64; d <<= 1) {
                int v = __shfl_up(incl, d, 64);
                if (lane >= d) incl += v;
            }
            if (lane == 63) s_wsum[wid] = incl;
            __syncthreads();
            if (t < 16) {
                int v = s_wsum[t];
                int inc2 = v;
                for (int d = 1; d < 16; d <<= 1) {
                    int u = __shfl_up(inc2, d, 16);
                    if (t >= d) inc2 += u;
                }
                s_woff[t] = inc2 - v;
                if (t == 15) s_newcnt = inc2;
            }
            __syncthreads();
            int excl = s_woff[wid] + (incl - pairv);
            if (b0 < cnt) s_cnt[b0] = excl;
            if (b1 < cnt) s_cnt[b1] = excl + c0;
        }
        __syncthreads();
        // stable within-bucket rank (by ascending j) + scatter
        for (int p = 0; p < 2; ++p) {
            int j = p * 1024 + t;
            int w = j >> 6;
            if ((s_F[w] >> (j & 63)) & 1ull) {
                int f = s_f[j];
                int r = 0;
                for (int w2 = 0; w2 <= w; ++w2) {
                    u64 m = s_F[w2];
                    if (w2 == w) m &= (1ull << (j & 63)) - 1ull;
                    while (m) {
                        int b = __ffsll(m) - 1;
                        m &= m - 1;
                        if (s_f[(w2 << 6) + b] == (unsigned short)f) ++r;
                    }
                }
                int slot = base + s_cnt[f] + r;
                s_pos[j] = (u16)slot;
                s_porder[slot] = j;
            }
        }
        if (t < NW) s_enq[t] |= s_F[t];
        __syncthreads();
        if (t == 0) { s_lo = base; s_levcnt = s_newcnt; s_base = base + s_newcnt; }
        __syncthreads();
    }

    // ---- finale: padding ranks for unreached (ascending j), then emit ----
    for (int p = 0; p < 2; ++p) {
        int j = p * 1024 + t;
        int w = j >> 6; u64 bit = 1ull << (j & 63);
        if (!((s_enq[w] >> (j & 63)) & 1ull)) {
            int rk = 0;
            for (int k2 = 0; k2 < w; ++k2) rk += __popcll(~s_enq[k2]);
            rk += __popcll(~s_enq[w] & (bit - 1ull));
            int slot = s_base + rk;
            s_pos[j] = (u16)slot;
            s_porder[slot] = j;
        }
    }
    __syncthreads();
    for (int p = 0; p < 2; ++p) {
        int j = p * 1024 + t;
        int fl = s_pos[j];
        if ((s_root[j >> 6] >> (j & 63)) & 1ull) fl |= 0x8000;
        if ((s_enq[j >> 6]  >> (j & 63)) & 1ull) fl |= 0x4000;
        posr[j] = (u16)fl;
        porderW[j] = (u16)s_porder[j];
    }
    if (t == 0) *nrPtr = s_nr;
}

// ---------------------------------------------------------------------------
// K3: bit-transpose heBits -> heT (heT[j] = in-edge mask of j, natural order)
// 64x64-bit tiles via ballots.
// ---------------------------------------------------------------------------
__global__ __launch_bounds__(64) void transpose_kernel(
    const u64* __restrict__ heBits, u64* __restrict__ heT)
{
    const int ti = blockIdx.x >> 5;
    const int tj = blockIdx.x & 31;
    const int r = threadIdx.x;
    u64 w = heBits[(size_t)(64 * ti + r) * NW + tj];
    u64 out = 0;
    #pragma unroll
    for (int b = 0; b < 64; ++b) {
        u64 m = __ballot(((w >> b) & 1ull) != 0);
        if (b == r) out = m;
    }
    heT[(size_t)(64 * tj + r) * NW + ti] = out;
}

// ---------------------------------------------------------------------------
// K4: permuted strict-lower parent matrix
//   Ap[b][a] = he[inv[a]][inv[b]] & (a < b) & (b >= nr)
// ---------------------------------------------------------------------------
__global__ __launch_bounds__(256) void apbuild_kernel(
    const u64* __restrict__ heT, const u16* __restrict__ porderW,
    const int* __restrict__ nrPtr, u64* __restrict__ Ap)
{
    __shared__ u64 s_row[NW];
    __shared__ u16 s_inv[NN];
    __shared__ int s_invb, s_nr;
    const int b = blockIdx.x;
    const int t = threadIdx.x;
    for (int q = t; q < NN; q += 256) s_inv[q] = porderW[q];
    if (t == 0) { s_invb = porderW[b]; s_nr = *nrPtr; }
    __syncthreads();
    if (t < NW) s_row[t] = heT[(size_t)s_invb * NW + t];
    __syncthreads();
    const bool bge = (b >= s_nr);
    for (int pass = 0; pass < 8; ++pass) {
        int a = pass * 256 + t;
        int ia = s_inv[a];
        bool bit = bge && (a < b) &&
                   (((s_row[ia >> 6] >> (ia & 63)) & 1ull) != 0);
        u64 m = __ballot(bit);
        if ((t & 63) == 0) Ap[(size_t)b * NW + (a >> 6)] = m;
    }
}

// ---------------------------------------------------------------------------
// K5: diagonal closures  Di[k] = closure(Ap_kk) (reflexive), 6 squarings
// ---------------------------------------------------------------------------
__global__ __launch_bounds__(64) void diag_kernel(
    const u64* __restrict__ Ap, u64* __restrict__ Di)
{
    __shared__ u64 sm[64];
    const int r = threadIdx.x;
    const int k = blockIdx.x;
    u64 M = Ap[(size_t)(64 * k + r) * NW + k] | (1ull << r);
    for (int s = 0; s < 6; ++s) {
        sm[r] = M;
        __syncthreads();
        u64 acc = 0;
        #pragma unroll
        for (int b = 0; b < 64; ++b)
            acc |= sm[b] & (0ull - ((M >> b) & 1ull));
        __syncthreads();
        M = acc;
    }
    Di[64 * k + r] = M;
}

// ---------------------------------------------------------------------------
// K6: blocked forward-substitution closure, one block per block-column k.
//   Anc_kk = Dk;  Anc_ik = Di * (sum_{k<=j<i} Ap_ij * Anc_jk)
// Each column independent; 16 waves split the j-sum; LDS broadcasts only.
// ---------------------------------------------------------------------------
__global__ __launch_bounds__(1024) void col_kernel(
    const u64* __restrict__ Ap, const u64* __restrict__ Di,
    u64* __restrict__ Anc)
{
    __shared__ u64 colA[32][64];   // Anc_jk rows, rel index j-k
    __shared__ u64 part[16][64];
    const int t = threadIdx.x;
    const int r = t & 63;
    const int wv = t >> 6;
    const int k = blockIdx.x;

    // rows above the diagonal block never get ancestors in column k -> zero
    for (int row = t; row < 64 * k; row += 1024)
        Anc[(size_t)row * NW + k] = 0ull;

    if (t < 64) {
        u64 d = Di[64 * k + r];
        colA[0][r] = d;
        Anc[(size_t)(64 * k + r) * NW + k] = d;
    }
    __syncthreads();

    for (int i = k + 1; i < 32; ++i) {
        int j0 = k + wv, j1 = k + wv + 16;
        u64 a0 = (j0 < i) ? Ap[(size_t)(64 * i + r) * NW + j0] : 0ull;
        u64 a1 = (j1 < i) ? Ap[(size_t)(64 * i + r) * NW + j1] : 0ull;
        u64 acc = 0;
        if (a0 | a1) {
            int r0 = j0 - k, r1 = j1 - k;   // <= 31
            #pragma unroll
            for (int b = 0; b < 64; ++b) {
                acc |= colA[r0][b] & (0ull - ((a0 >> b) & 1ull));
                acc |= colA[r1][b] & (0ull - ((a1 >> b) & 1ull));
            }
        }
        part[wv][r] = acc;
        __syncthreads();
        if (wv == 0) {
            u64 red = 0;
            #pragma unroll
            for (int w = 0; w < 16; ++w) red |= part[w][r];
            u64 d = Di[64 * i + r];
            u64 acc2 = 0;
            #pragma unroll
            for (int b = 0; b < 64; ++b) {
                u64 vb = __shfl(red, b, 64);
                acc2 |= vb & (0ull - ((d >> b) & 1ull));
            }
            colA[i - k][r] = acc2;
            Anc[(size_t)(64 * i + r) * NW + k] = acc2;
        }
        __syncthreads();
    }
}

// ---------------------------------------------------------------------------
// K7: output. he recomputed from inputs; forbidden = root[j] | ancbit | !reach_i
// ---------------------------------------------------------------------------
__global__ __launch_bounds__(256) void out_kernel(
    const float* __restrict__ edge_logits,
    const float* __restrict__ g_edge,
    const u64* __restrict__ Anc,
    const u16* __restrict__ posr,
    float* __restrict__ dag)
{
    __shared__ u64 s_anc[NW];
    __shared__ int s_pi, s_fl;
    const int i = blockIdx.x;
    const int t = threadIdx.x;
    if (t == 0) { int pr = posr[i]; s_pi = pr & 0x7FF; s_fl = pr; }
    __syncthreads();
    if (t < NW) s_anc[t] = Anc[(size_t)s_pi * NW + t];
    __syncthreads();
    const bool reach_i = (s_fl & 0x4000) != 0;
    const int j0 = t * 8;

    const float4* xe  = (const float4*)(edge_logits + (size_t)i * NN + j0);
    const float4* ge0 = (const float4*)(g_edge + (size_t)i * (2 * NN) + j0);
    const float4* ge1 = (const float4*)(g_edge + (size_t)i * (2 * NN) + NN + j0);
    float4 xa = xe[0],  xb = xe[1];
    float4 g0a = ge0[0], g0b = ge0[1];
    float4 g1a = ge1[0], g1b = ge1[1];
    float x[8]  = {xa.x, xa.y, xa.z, xa.w, xb.x, xb.y, xb.z, xb.w};
    float g0[8] = {g0a.x, g0a.y, g0a.z, g0a.w, g0b.x, g0b.y, g0b.z, g0b.w};
    float g1[8] = {g1a.x, g1a.y, g1a.z, g1a.w, g1b.x, g1b.y, g1b.z, g1b.w};

    int4 pv = *(const int4*)(posr + j0);
    int pw[4] = {pv.x, pv.y, pv.z, pv.w};

    float o[8];
    #pragma unroll
    for (int e = 0; e < 8; ++e) {
        int pr = (pw[e >> 1] >> ((e & 1) * 16)) & 0xFFFF;
        bool he = gumbel_gt(x[e], g0[e], g1[e]);
        bool root_j = (pr & 0x8000) != 0;
        int a = pr & 0x7FF;
        bool anc = ((s_anc[a >> 6] >> (a & 63)) & 1ull) != 0;
        o[e] = (reach_i && he && !root_j && !anc) ? 1.f : 0.f;
    }
    float4* outp = (float4*)(dag + (size_t)i * NN + j0);
    outp[0] = make_float4(o[0], o[1], o[2], o[3]);
    outp[1] = make_float4(o[4], o[5], o[6], o[7]);
}

// ---------------------------------------------------------------------------
extern "C" void kernel_launch(void* const* d_in, const int* in_sizes, int n_in,
                              void* d_out, int out_size, void* d_ws, size_t ws_size,
                              hipStream_t stream) {
    const float* root_logits = (const float*)d_in[0];
    const float* edge_logits = (const float*)d_in[1];
    const float* g_root      = (const float*)d_in[2];
    const float* g_edge      = (const float*)d_in[3];
    float* dag = (float*)d_out;

    // d_ws (<= 1 MB, proven available):
    //   [0, 512K): heBits (prep -> transpose), then Anc (col -> out)
    u64* heBits = (u64*)d_ws;
    u64* Anc    = (u64*)d_ws;
    u16* posr    = (u16*)((char*)d_ws + (512 << 10));   // 4 KB (order -> out)
    u16* porderW = (u16*)((char*)d_ws + (516 << 10));   // 4 KB (order -> apbuild)
    int* nrPtr   = (int*)((char*)d_ws + (520 << 10));   // 4 B
    // d_out tail as early scratch (dead before out_kernel, which rewrites all):
    u64* heT = (u64*)((char*)d_out + (1 << 20));               // 512 KB
    u64* Ap  = (u64*)((char*)d_out + (1 << 20) + (512 << 10)); // 512 KB
    u64* Di  = (u64*)((char*)d_out + (2 << 20));               // 16 KB

    prep_kernel     <<<NN, 256, 0, stream>>>(edge_logits, g_edge, heBits);
    order_kernel    <<<1, 1024, 0, stream>>>(root_logits, g_root, heBits,
                                             posr, porderW, nrPtr);
    transpose_kernel<<<NN / 2, 64, 0, stream>>>(heBits, heT);
    apbuild_kernel  <<<NN, 256, 0, stream>>>(heT, porderW, nrPtr, Ap);
    diag_kernel     <<<NW, 64, 0, stream>>>(Ap, Di);
    col_kernel      <<<NW, 1024, 0, stream>>>(Ap, Di, Anc);
    out_kernel      <<<NN, 256, 0, stream>>>(edge_logits, g_edge, Anc, posr, dag);
}

// Round 4
// 222.028 us; speedup vs baseline: 33.5165x; 1.5201x over previous
//
#include <hip/hip_runtime.h>
#include <stdint.h>

typedef unsigned long long u64;
typedef unsigned short u16;

#define NN 2048
#define NW 32    // u64 words per 2048-bit row

static __device__ __forceinline__ bool gumbel_gt(float x, float g0, float g1) {
    // jax.nn.log_sigmoid(x) = -(max(-x,0) + log1p(exp(-|x|)))
    float L = log1pf(expf(-fabsf(x)));
    float a = (-(fmaxf(-x, 0.f) + L)) + g0;   // ye[0]
    float b = (-(fmaxf( x, 0.f) + L)) + g1;   // ye[1]
    return a > b;
}

// ---------------------------------------------------------------------------
// K1: hard-edge bitmask  he[i][j]
// ---------------------------------------------------------------------------
__global__ __launch_bounds__(256) void prep_kernel(
    const float* __restrict__ edge_logits,
    const float* __restrict__ g_edge,
    u64* __restrict__ heBits)
{
    const int i = blockIdx.x;
    const int t = threadIdx.x;
    const int lane = t & 63;
    const int wave = t >> 6;
    for (int c = wave; c < NW; c += 4) {
        int j = (c << 6) + lane;
        float x  = edge_logits[(size_t)i * NN + j];
        float g0 = g_edge[(size_t)i * (2 * NN) + j];
        float g1 = g_edge[(size_t)i * (2 * NN) + NN + j];
        u64 m = __ballot(gumbel_gt(x, g0, g1));
        if (lane == 0) heBits[(size_t)i * NW + c] = m;
    }
}

// ---------------------------------------------------------------------------
// K2: level-synchronous BFS order, v2.
// Within-level order = (first-parent rank f, node index j). Buckets are
// computed as prefix-OR masks: B_f = row_f & F & ~(OR of earlier rows & F),
// which partition F exactly. 16 contiguous segments scanned in parallel.
// Emits: posr[j] = pos | root<<15 | reach<<14 ; porderW ; nr.
// ---------------------------------------------------------------------------
__global__ __launch_bounds__(1024) void order_kernel(
    const float* __restrict__ root_logits,
    const float* __restrict__ g_root,
    const u64* __restrict__ heBits,
    u16* __restrict__ posr,
    u16* __restrict__ porderW,
    int* __restrict__ nrPtr)
{
    __shared__ u64 s_root[NW], s_enq[NW], s_F[NW];
    __shared__ u64 s_U[16][NW];      // per-segment OR of member rows
    __shared__ u64 s_Pg[16][NW];     // per-segment prefix (earlier segs) & F
    __shared__ int s_porder[NN];
    __shared__ u16 s_pos[NN];
    __shared__ u16 s_f[NN];          // bucket (member rank) per frontier node
    __shared__ u16 s_rk[NN];         // rank within bucket
    __shared__ int s_cnt[NN];
    __shared__ int s_wsum[16], s_woff[16];
    __shared__ int s_base, s_lo, s_levcnt, s_newcnt, s_nr;

    const int t    = threadIdx.x;
    const int lane = t & 63;
    const int wid  = t >> 6;      // wave 0..15
    const int half = lane >> 5;   // 0/1
    const int w    = lane & 31;   // word index

    // ---- root bits ----
    for (int p = 0; p < 2; ++p) {
        int j = p * 1024 + t;
        bool rb = gumbel_gt(root_logits[j], g_root[j], g_root[NN + j]);
        u64 m = __ballot(rb);
        if (lane == 0) s_root[j >> 6] = m;
    }
    __syncthreads();
    // ---- level 0 = roots ascending ----
    for (int p = 0; p < 2; ++p) {
        int j = p * 1024 + t;
        int ww = j >> 6; u64 bit = 1ull << (j & 63);
        if (s_root[ww] & bit) {
            int r = 0;
            for (int k = 0; k < ww; ++k) r += __popcll(s_root[k]);
            r += __popcll(s_root[ww] & (bit - 1ull));
            s_pos[j] = (u16)r;
            s_porder[r] = j;
        }
    }
    if (t < NW) s_enq[t] = s_root[t];
    if (t == 0) {
        int tl = 0;
        for (int k = 0; k < NW; ++k) tl += __popcll(s_root[k]);
        s_lo = 0; s_levcnt = tl; s_base = tl; s_nr = tl;
    }
    __syncthreads();

    while (s_levcnt > 0 && s_base < NN) {
        const int lo = s_lo, cnt = s_levcnt, base = s_base;
        const int seglen = (cnt + 15) >> 4;
        const int s0 = wid * seglen;
        const int s1 = (s0 + seglen < cnt) ? (s0 + seglen) : cnt;

        // Phase A: per-segment OR of member he-rows (2 members per step)
        {
            u64 acc = 0;
            for (int m = s0 + half; m < s1; m += 2)
                acc |= heBits[(size_t)s_porder[lo + m] * NW + w];
            acc |= __shfl(acc, lane ^ 32);
            if (half == 0) s_U[wid][w] = acc;
        }
        __syncthreads();
        // Phase B: frontier F, then per-segment prefix masks
        if (t < NW) {
            u64 o = 0;
            #pragma unroll
            for (int s = 0; s < 16; ++s) o |= s_U[s][t];
            s_F[t] = o & ~s_enq[t] & ~s_root[t];
        }
        __syncthreads();
        if (t < 512) {
            int s = t >> 5, ww = t & 31;
            u64 p = 0;
            for (int s2 = 0; s2 < s; ++s2) p |= s_U[s2][ww];
            s_Pg[s][ww] = p & s_F[ww];
        }
        __syncthreads();
        // Phase C: serial bucket scan per segment (2 members/step, halves)
        {
            u64 P  = s_Pg[wid][w];
            u64 Fw = s_F[w];
            int myidx = (s0 + lane < s1) ? s_porder[lo + s0 + lane] : 0;
            for (int m = s0; m < s1; m += 2) {
                int m0 = m + half;
                int rowi = __shfl(myidx, (m - s0) + half);
                u64 r = 0;
                if (m0 < s1) r = heBits[(size_t)rowi * NW + w];
                u64 v = r & Fw & ~P;
                u64 vlo = __shfl(v, w);               // low half's word w
                u64 B = half ? (v & ~vlo) : v;        // dedupe within pair
                int pc = __popcll(B);
                int inc = pc;
                #pragma unroll
                for (int d = 1; d < 32; d <<= 1) {
                    int u2 = __shfl_up(inc, d, 64);
                    if (w >= d) inc += u2;
                }
                int excl = inc - pc;
                int tot = __shfl(inc, (half << 5) | 31);
                if (w == 0 && m0 < s1) s_cnt[m0] = tot;
                u64 mm = B;
                int idx = excl;
                while (mm) {
                    int b = __ffsll(mm) - 1; mm &= mm - 1;
                    int j = (w << 6) + b;
                    s_f[j]  = (u16)m0;
                    s_rk[j] = (u16)idx++;
                }
                P |= B | __shfl(B, lane ^ 32);
            }
        }
        __syncthreads();
        // Phase D: exclusive prefix over s_cnt[0..cnt)
        {
            int b0 = 2 * t, b1 = 2 * t + 1;
            int c0 = (b0 < cnt) ? s_cnt[b0] : 0;
            int c1 = (b1 < cnt) ? s_cnt[b1] : 0;
            int pairv = c0 + c1;
            int incl = pairv;
            for (int d = 1; d < 64; d <<= 1) {
                int v = __shfl_up(incl, d, 64);
                if (lane >= d) incl += v;
            }
            if (lane == 63) s_wsum[wid] = incl;
            __syncthreads();
            if (t < 16) {
                int v = s_wsum[t];
                int inc2 = v;
                for (int d = 1; d < 16; d <<= 1) {
                    int u = __shfl_up(inc2, d, 16);
                    if (t >= d) inc2 += u;
                }
                s_woff[t] = inc2 - v;
                if (t == 15) s_newcnt = inc2;
            }
            __syncthreads();
            int excl = s_woff[wid] + (incl - pairv);
            if (b0 < cnt) s_cnt[b0] = excl;
            if (b1 < cnt) s_cnt[b1] = excl + c0;
        }
        __syncthreads();
        // Phase E: parallel placement
        for (int p = 0; p < 2; ++p) {
            int j = p * 1024 + t;
            int ww = j >> 6;
            if ((s_F[ww] >> (j & 63)) & 1ull) {
                int slot = base + s_cnt[s_f[j]] + s_rk[j];
                s_pos[j] = (u16)slot;
                s_porder[slot] = j;
            }
        }
        if (t < NW) s_enq[t] |= s_F[t];
        __syncthreads();
        if (t == 0) { s_lo = base; s_levcnt = s_newcnt; s_base = base + s_newcnt; }
        __syncthreads();
    }

    // ---- finale: padding ranks for unreached (ascending j), then emit ----
    for (int p = 0; p < 2; ++p) {
        int j = p * 1024 + t;
        int ww = j >> 6; u64 bit = 1ull << (j & 63);
        if (!((s_enq[ww] >> (j & 63)) & 1ull)) {
            int rk = 0;
            for (int k2 = 0; k2 < ww; ++k2) rk += __popcll(~s_enq[k2]);
            rk += __popcll(~s_enq[ww] & (bit - 1ull));
            int slot = s_base + rk;
            s_pos[j] = (u16)slot;
            s_porder[slot] = j;
        }
    }
    __syncthreads();
    for (int p = 0; p < 2; ++p) {
        int j = p * 1024 + t;
        int fl = s_pos[j];
        if ((s_root[j >> 6] >> (j & 63)) & 1ull) fl |= 0x8000;
        if ((s_enq[j >> 6]  >> (j & 63)) & 1ull) fl |= 0x4000;
        posr[j] = (u16)fl;
        porderW[j] = (u16)s_porder[j];
    }
    if (t == 0) *nrPtr = s_nr;
}

// ---------------------------------------------------------------------------
// K3: bit-transpose heBits -> heT (heT[j] = in-edge mask of j, natural order)
// ---------------------------------------------------------------------------
__global__ __launch_bounds__(64) void transpose_kernel(
    const u64* __restrict__ heBits, u64* __restrict__ heT)
{
    const int ti = blockIdx.x >> 5;
    const int tj = blockIdx.x & 31;
    const int r = threadIdx.x;
    u64 w = heBits[(size_t)(64 * ti + r) * NW + tj];
    u64 out = 0;
    #pragma unroll
    for (int b = 0; b < 64; ++b) {
        u64 m = __ballot(((w >> b) & 1ull) != 0);
        if (b == r) out = m;
    }
    heT[(size_t)(64 * tj + r) * NW + ti] = out;
}

// ---------------------------------------------------------------------------
// K4: permuted strict-lower parent matrix
//   Ap[b][a] = he[inv[a]][inv[b]] & (a < b) & (b >= nr)
// ---------------------------------------------------------------------------
__global__ __launch_bounds__(256) void apbuild_kernel(
    const u64* __restrict__ heT, const u16* __restrict__ porderW,
    const int* __restrict__ nrPtr, u64* __restrict__ Ap)
{
    __shared__ u64 s_row[NW];
    __shared__ u16 s_inv[NN];
    __shared__ int s_invb, s_nr;
    const int b = blockIdx.x;
    const int t = threadIdx.x;
    for (int q = t; q < NN; q += 256) s_inv[q] = porderW[q];
    if (t == 0) { s_invb = porderW[b]; s_nr = *nrPtr; }
    __syncthreads();
    if (t < NW) s_row[t] = heT[(size_t)s_invb * NW + t];
    __syncthreads();
    const bool bge = (b >= s_nr);
    for (int pass = 0; pass < 8; ++pass) {
        int a = pass * 256 + t;
        int ia = s_inv[a];
        bool bit = bge && (a < b) &&
                   (((s_row[ia >> 6] >> (ia & 63)) & 1ull) != 0);
        u64 m = __ballot(bit);
        if ((t & 63) == 0) Ap[(size_t)b * NW + (a >> 6)] = m;
    }
}

// ---------------------------------------------------------------------------
// K5: diagonal closures  Di[k] = closure(Ap_kk) (reflexive), 6 squarings
// ---------------------------------------------------------------------------
__global__ __launch_bounds__(64) void diag_kernel(
    const u64* __restrict__ Ap, u64* __restrict__ Di)
{
    __shared__ u64 sm[64];
    const int r = threadIdx.x;
    const int k = blockIdx.x;
    u64 M = Ap[(size_t)(64 * k + r) * NW + k] | (1ull << r);
    for (int s = 0; s < 6; ++s) {
        sm[r] = M;
        __syncthreads();
        u64 acc = 0;
        #pragma unroll
        for (int b = 0; b < 64; ++b)
            acc |= sm[b] & (0ull - ((M >> b) & 1ull));
        __syncthreads();
        M = acc;
    }
    Di[64 * k + r] = M;
}

// ---------------------------------------------------------------------------
// K6: blocked forward-substitution closure, one block per block-column k.
// ---------------------------------------------------------------------------
__global__ __launch_bounds__(1024) void col_kernel(
    const u64* __restrict__ Ap, const u64* __restrict__ Di,
    u64* __restrict__ Anc)
{
    __shared__ u64 colA[32][64];
    __shared__ u64 part[16][64];
    const int t = threadIdx.x;
    const int r = t & 63;
    const int wv = t >> 6;
    const int k = blockIdx.x;

    for (int row = t; row < 64 * k; row += 1024)
        Anc[(size_t)row * NW + k] = 0ull;

    if (t < 64) {
        u64 d = Di[64 * k + r];
        colA[0][r] = d;
        Anc[(size_t)(64 * k + r) * NW + k] = d;
    }
    __syncthreads();

    for (int i = k + 1; i < 32; ++i) {
        int j0 = k + wv, j1 = k + wv + 16;
        u64 a0 = (j0 < i) ? Ap[(size_t)(64 * i + r) * NW + j0] : 0ull;
        u64 a1 = (j1 < i) ? Ap[(size_t)(64 * i + r) * NW + j1] : 0ull;
        u64 acc = 0;
        if (a0 | a1) {
            int r0 = j0 - k, r1 = j1 - k;
            #pragma unroll
            for (int b = 0; b < 64; ++b) {
                acc |= colA[r0][b] & (0ull - ((a0 >> b) & 1ull));
                acc |= colA[r1][b] & (0ull - ((a1 >> b) & 1ull));
            }
        }
        part[wv][r] = acc;
        __syncthreads();
        if (wv == 0) {
            u64 red = 0;
            #pragma unroll
            for (int w = 0; w < 16; ++w) red |= part[w][r];
            u64 d = Di[64 * i + r];
            u64 acc2 = 0;
            #pragma unroll
            for (int b = 0; b < 64; ++b) {
                u64 vb = __shfl(red, b, 64);
                acc2 |= vb & (0ull - ((d >> b) & 1ull));
            }
            colA[i - k][r] = acc2;
            Anc[(size_t)(64 * i + r) * NW + k] = acc2;
        }
        __syncthreads();
    }
}

// ---------------------------------------------------------------------------
// K7: output. he recomputed from inputs; forbidden = root[j] | ancbit | !reach_i
// ---------------------------------------------------------------------------
__global__ __launch_bounds__(256) void out_kernel(
    const float* __restrict__ edge_logits,
    const float* __restrict__ g_edge,
    const u64* __restrict__ Anc,
    const u16* __restrict__ posr,
    float* __restrict__ dag)
{
    __shared__ u64 s_anc[NW];
    __shared__ int s_pi, s_fl;
    const int i = blockIdx.x;
    const int t = threadIdx.x;
    if (t == 0) { int pr = posr[i]; s_pi = pr & 0x7FF; s_fl = pr; }
    __syncthreads();
    if (t < NW) s_anc[t] = Anc[(size_t)s_pi * NW + t];
    __syncthreads();
    const bool reach_i = (s_fl & 0x4000) != 0;
    const int j0 = t * 8;

    const float4* xe  = (const float4*)(edge_logits + (size_t)i * NN + j0);
    const float4* ge0 = (const float4*)(g_edge + (size_t)i * (2 * NN) + j0);
    const float4* ge1 = (const float4*)(g_edge + (size_t)i * (2 * NN) + NN + j0);
    float4 xa = xe[0],  xb = xe[1];
    float4 g0a = ge0[0], g0b = ge0[1];
    float4 g1a = ge1[0], g1b = ge1[1];
    float x[8]  = {xa.x, xa.y, xa.z, xa.w, xb.x, xb.y, xb.z, xb.w};
    float g0[8] = {g0a.x, g0a.y, g0a.z, g0a.w, g0b.x, g0b.y, g0b.z, g0b.w};
    float g1[8] = {g1a.x, g1a.y, g1a.z, g1a.w, g1b.x, g1b.y, g1b.z, g1b.w};

    int4 pv = *(const int4*)(posr + j0);
    int pw[4] = {pv.x, pv.y, pv.z, pv.w};

    float o[8];
    #pragma unroll
    for (int e = 0; e < 8; ++e) {
        int pr = (pw[e >> 1] >> ((e & 1) * 16)) & 0xFFFF;
        bool he = gumbel_gt(x[e], g0[e], g1[e]);
        bool root_j = (pr & 0x8000) != 0;
        int a = pr & 0x7FF;
        bool anc = ((s_anc[a >> 6] >> (a & 63)) & 1ull) != 0;
        o[e] = (reach_i && he && !root_j && !anc) ? 1.f : 0.f;
    }
    float4* outp = (float4*)(dag + (size_t)i * NN + j0);
    outp[0] = make_float4(o[0], o[1], o[2], o[3]);
    outp[1] = make_float4(o[4], o[5], o[6], o[7]);
}

// ---------------------------------------------------------------------------
extern "C" void kernel_launch(void* const* d_in, const int* in_sizes, int n_in,
                              void* d_out, int out_size, void* d_ws, size_t ws_size,
                              hipStream_t stream) {
    const float* root_logits = (const float*)d_in[0];
    const float* edge_logits = (const float*)d_in[1];
    const float* g_root      = (const float*)d_in[2];
    const float* g_edge      = (const float*)d_in[3];
    float* dag = (float*)d_out;

    u64* heBits = (u64*)d_ws;
    u64* Anc    = (u64*)d_ws;
    u16* posr    = (u16*)((char*)d_ws + (512 << 10));
    u16* porderW = (u16*)((char*)d_ws + (516 << 10));
    int* nrPtr   = (int*)((char*)d_ws + (520 << 10));
    u64* heT = (u64*)((char*)d_out + (1 << 20));
    u64* Ap  = (u64*)((char*)d_out + (1 << 20) + (512 << 10));
    u64* Di  = (u64*)((char*)d_out + (2 << 20));

    prep_kernel     <<<NN, 256, 0, stream>>>(edge_logits, g_edge, heBits);
    order_kernel    <<<1, 1024, 0, stream>>>(root_logits, g_root, heBits,
                                             posr, porderW, nrPtr);
    transpose_kernel<<<NN / 2, 64, 0, stream>>>(heBits, heT);
    apbuild_kernel  <<<NN, 256, 0, stream>>>(heT, porderW, nrPtr, Ap);
    diag_kernel     <<<NW, 64, 0, stream>>>(Ap, Di);
    col_kernel      <<<NW, 1024, 0, stream>>>(Ap, Di, Anc);
    out_kernel      <<<NN, 256, 0, stream>>>(edge_logits, g_edge, Anc, posr, dag);
}

// Round 5
// 186.131 us; speedup vs baseline: 39.9804x; 1.1929x over previous
//
#include <hip/hip_runtime.h>
#include <stdint.h>

typedef unsigned long long u64;
typedef unsigned int u32;
typedef unsigned short u16;

#define NN 2048
#define NW 32    // u64 words per 2048-bit row

#if __has_builtin(__builtin_amdgcn_sbfe)
#define SBFE(x, o) ((u32)__builtin_amdgcn_sbfe((int)(x), (u32)(o), 1u))
#else
#define SBFE(x, o) ((u32)(-(int)(((x) >> (o)) & 1u)))
#endif

static __device__ __forceinline__ bool gumbel_gt(float x, float g0, float g1) {
    // jax.nn.log_sigmoid(x) = -(max(-x,0) + log1p(exp(-|x|)))
    float L = log1pf(expf(-fabsf(x)));
    float a = (-(fmaxf(-x, 0.f) + L)) + g0;   // ye[0]
    float b = (-(fmaxf( x, 0.f) + L)) + g1;   // ye[1]
    return a > b;
}

// acc |= (bit b0 of m ? w0 : 0) | (bit b0+1 of m ? w1 : 0); b0 even, compile-time
static __device__ __forceinline__ u64 orsel2(u64 acc, u64 w0, u64 w1, u64 m, int b0) {
    u32 mm = (b0 < 32) ? (u32)m : (u32)(m >> 32);
    int sh = b0 & 31;
    u32 s0 = SBFE(mm, sh);
    u32 s1 = SBFE(mm, sh + 1);
    u32 al = (u32)acc | ((u32)w0 & s0) | ((u32)w1 & s1);
    u32 ah = (u32)(acc >> 32) | ((u32)(w0 >> 32) & s0) | ((u32)(w1 >> 32) & s1);
    return ((u64)ah << 32) | al;
}

// ---------------------------------------------------------------------------
// K1: hard-edge bitmask  he[i][j]
// ---------------------------------------------------------------------------
__global__ __launch_bounds__(256) void prep_kernel(
    const float* __restrict__ edge_logits,
    const float* __restrict__ g_edge,
    u64* __restrict__ heBits)
{
    const int i = blockIdx.x;
    const int t = threadIdx.x;
    const int lane = t & 63;
    const int wave = t >> 6;
    for (int c = wave; c < NW; c += 4) {
        int j = (c << 6) + lane;
        float x  = edge_logits[(size_t)i * NN + j];
        float g0 = g_edge[(size_t)i * (2 * NN) + j];
        float g1 = g_edge[(size_t)i * (2 * NN) + NN + j];
        u64 m = __ballot(gumbel_gt(x, g0, g1));
        if (lane == 0) heBits[(size_t)i * NW + c] = m;
    }
}

// ---------------------------------------------------------------------------
// K2: level-synchronous BFS order (unchanged from round 4 — proven).
// ---------------------------------------------------------------------------
__global__ __launch_bounds__(1024) void order_kernel(
    const float* __restrict__ root_logits,
    const float* __restrict__ g_root,
    const u64* __restrict__ heBits,
    u16* __restrict__ posr,
    u16* __restrict__ porderW,
    int* __restrict__ nrPtr)
{
    __shared__ u64 s_root[NW], s_enq[NW], s_F[NW];
    __shared__ u64 s_U[16][NW];
    __shared__ u64 s_Pg[16][NW];
    __shared__ int s_porder[NN];
    __shared__ u16 s_pos[NN];
    __shared__ u16 s_f[NN];
    __shared__ u16 s_rk[NN];
    __shared__ int s_cnt[NN];
    __shared__ int s_wsum[16], s_woff[16];
    __shared__ int s_base, s_lo, s_levcnt, s_newcnt, s_nr;

    const int t    = threadIdx.x;
    const int lane = t & 63;
    const int wid  = t >> 6;
    const int half = lane >> 5;
    const int w    = lane & 31;

    for (int p = 0; p < 2; ++p) {
        int j = p * 1024 + t;
        bool rb = gumbel_gt(root_logits[j], g_root[j], g_root[NN + j]);
        u64 m = __ballot(rb);
        if (lane == 0) s_root[j >> 6] = m;
    }
    __syncthreads();
    for (int p = 0; p < 2; ++p) {
        int j = p * 1024 + t;
        int ww = j >> 6; u64 bit = 1ull << (j & 63);
        if (s_root[ww] & bit) {
            int r = 0;
            for (int k = 0; k < ww; ++k) r += __popcll(s_root[k]);
            r += __popcll(s_root[ww] & (bit - 1ull));
            s_pos[j] = (u16)r;
            s_porder[r] = j;
        }
    }
    if (t < NW) s_enq[t] = s_root[t];
    if (t == 0) {
        int tl = 0;
        for (int k = 0; k < NW; ++k) tl += __popcll(s_root[k]);
        s_lo = 0; s_levcnt = tl; s_base = tl; s_nr = tl;
    }
    __syncthreads();

    while (s_levcnt > 0 && s_base < NN) {
        const int lo = s_lo, cnt = s_levcnt, base = s_base;
        const int seglen = (cnt + 15) >> 4;
        const int s0 = wid * seglen;
        const int s1 = (s0 + seglen < cnt) ? (s0 + seglen) : cnt;

        {
            u64 acc = 0;
            for (int m = s0 + half; m < s1; m += 2)
                acc |= heBits[(size_t)s_porder[lo + m] * NW + w];
            acc |= __shfl(acc, lane ^ 32);
            if (half == 0) s_U[wid][w] = acc;
        }
        __syncthreads();
        if (t < NW) {
            u64 o = 0;
            #pragma unroll
            for (int s = 0; s < 16; ++s) o |= s_U[s][t];
            s_F[t] = o & ~s_enq[t] & ~s_root[t];
        }
        __syncthreads();
        if (t < 512) {
            int s = t >> 5, ww = t & 31;
            u64 p = 0;
            for (int s2 = 0; s2 < s; ++s2) p |= s_U[s2][ww];
            s_Pg[s][ww] = p & s_F[ww];
        }
        __syncthreads();
        {
            u64 P  = s_Pg[wid][w];
            u64 Fw = s_F[w];
            int myidx = (s0 + lane < s1) ? s_porder[lo + s0 + lane] : 0;
            for (int m = s0; m < s1; m += 2) {
                int m0 = m + half;
                int rowi = __shfl(myidx, (m - s0) + half);
                u64 r = 0;
                if (m0 < s1) r = heBits[(size_t)rowi * NW + w];
                u64 v = r & Fw & ~P;
                u64 vlo = __shfl(v, w);
                u64 B = half ? (v & ~vlo) : v;
                int pc = __popcll(B);
                int inc = pc;
                #pragma unroll
                for (int d = 1; d < 32; d <<= 1) {
                    int u2 = __shfl_up(inc, d, 64);
                    if (w >= d) inc += u2;
                }
                int excl = inc - pc;
                int tot = __shfl(inc, (half << 5) | 31);
                if (w == 0 && m0 < s1) s_cnt[m0] = tot;
                u64 mm = B;
                int idx = excl;
                while (mm) {
                    int b = __ffsll(mm) - 1; mm &= mm - 1;
                    int j = (w << 6) + b;
                    s_f[j]  = (u16)m0;
                    s_rk[j] = (u16)idx++;
                }
                P |= B | __shfl(B, lane ^ 32);
            }
        }
        __syncthreads();
        {
            int b0 = 2 * t, b1 = 2 * t + 1;
            int c0 = (b0 < cnt) ? s_cnt[b0] : 0;
            int c1 = (b1 < cnt) ? s_cnt[b1] : 0;
            int pairv = c0 + c1;
            int incl = pairv;
            for (int d = 1; d < 64; d <<= 1) {
                int v = __shfl_up(incl, d, 64);
                if (lane >= d) incl += v;
            }
            if (lane == 63) s_wsum[wid] = incl;
            __syncthreads();
            if (t < 16) {
                int v = s_wsum[t];
                int inc2 = v;
                for (int d = 1; d < 16; d <<= 1) {
                    int u = __shfl_up(inc2, d, 16);
                    if (t >= d) inc2 += u;
                }
                s_woff[t] = inc2 - v;
                if (t == 15) s_newcnt = inc2;
            }
            __syncthreads();
            int excl = s_woff[wid] + (incl - pairv);
            if (b0 < cnt) s_cnt[b0] = excl;
            if (b1 < cnt) s_cnt[b1] = excl + c0;
        }
        __syncthreads();
        for (int p = 0; p < 2; ++p) {
            int j = p * 1024 + t;
            int ww = j >> 6;
            if ((s_F[ww] >> (j & 63)) & 1ull) {
                int slot = base + s_cnt[s_f[j]] + s_rk[j];
                s_pos[j] = (u16)slot;
                s_porder[slot] = j;
            }
        }
        if (t < NW) s_enq[t] |= s_F[t];
        __syncthreads();
        if (t == 0) { s_lo = base; s_levcnt = s_newcnt; s_base = base + s_newcnt; }
        __syncthreads();
    }

    for (int p = 0; p < 2; ++p) {
        int j = p * 1024 + t;
        int ww = j >> 6; u64 bit = 1ull << (j & 63);
        if (!((s_enq[ww] >> (j & 63)) & 1ull)) {
            int rk = 0;
            for (int k2 = 0; k2 < ww; ++k2) rk += __popcll(~s_enq[k2]);
            rk += __popcll(~s_enq[ww] & (bit - 1ull));
            int slot = s_base + rk;
            s_pos[j] = (u16)slot;
            s_porder[slot] = j;
        }
    }
    __syncthreads();
    for (int p = 0; p < 2; ++p) {
        int j = p * 1024 + t;
        int fl = s_pos[j];
        if ((s_root[j >> 6] >> (j & 63)) & 1ull) fl |= 0x8000;
        if ((s_enq[j >> 6]  >> (j & 63)) & 1ull) fl |= 0x4000;
        posr[j] = (u16)fl;
        porderW[j] = (u16)s_porder[j];
    }
    if (t == 0) *nrPtr = s_nr;
}

// ---------------------------------------------------------------------------
// K3: bit-transpose heBits -> heT
// ---------------------------------------------------------------------------
__global__ __launch_bounds__(64) void transpose_kernel(
    const u64* __restrict__ heBits, u64* __restrict__ heT)
{
    const int ti = blockIdx.x >> 5;
    const int tj = blockIdx.x & 31;
    const int r = threadIdx.x;
    u64 w = heBits[(size_t)(64 * ti + r) * NW + tj];
    u64 out = 0;
    #pragma unroll
    for (int b = 0; b < 64; ++b) {
        u64 m = __ballot(((w >> b) & 1ull) != 0);
        if (b == r) out = m;
    }
    heT[(size_t)(64 * tj + r) * NW + ti] = out;
}

// ---------------------------------------------------------------------------
// K4: permuted strict-lower parent matrix
// ---------------------------------------------------------------------------
__global__ __launch_bounds__(256) void apbuild_kernel(
    const u64* __restrict__ heT, const u16* __restrict__ porderW,
    const int* __restrict__ nrPtr, u64* __restrict__ Ap)
{
    __shared__ u64 s_row[NW];
    __shared__ u16 s_inv[NN];
    __shared__ int s_invb, s_nr;
    const int b = blockIdx.x;
    const int t = threadIdx.x;
    for (int q = t; q < NN; q += 256) s_inv[q] = porderW[q];
    if (t == 0) { s_invb = porderW[b]; s_nr = *nrPtr; }
    __syncthreads();
    if (t < NW) s_row[t] = heT[(size_t)s_invb * NW + t];
    __syncthreads();
    const bool bge = (b >= s_nr);
    for (int pass = 0; pass < 8; ++pass) {
        int a = pass * 256 + t;
        int ia = s_inv[a];
        bool bit = bge && (a < b) &&
                   (((s_row[ia >> 6] >> (ia & 63)) & 1ull) != 0);
        u64 m = __ballot(bit);
        if ((t & 63) == 0) Ap[(size_t)b * NW + (a >> 6)] = m;
    }
}

// ---------------------------------------------------------------------------
// K5: diagonal closures  Di[k] = closure(Ap_kk) (reflexive), 6 squarings
// ---------------------------------------------------------------------------
__global__ __launch_bounds__(64) void diag_kernel(
    const u64* __restrict__ Ap, u64* __restrict__ Di)
{
    __shared__ u64 sm[64];
    const int r = threadIdx.x;
    const int k = blockIdx.x;
    u64 M = Ap[(size_t)(64 * k + r) * NW + k] | (1ull << r);
    for (int s = 0; s < 6; ++s) {
        sm[r] = M;
        __syncthreads();
        u64 acc = 0;
        #pragma unroll
        for (int b = 0; b < 64; ++b)
            acc |= sm[b] & (0ull - ((M >> b) & 1ull));
        __syncthreads();
        M = acc;
    }
    Di[64 * k + r] = M;
}

// ---------------------------------------------------------------------------
// K5b: premultiply Ap_ij := Di * Ap_ij for all j < i (in place, per-block safe)
// ---------------------------------------------------------------------------
__global__ __launch_bounds__(64) void ap2_kernel(
    const u64* __restrict__ Di, u64* __restrict__ Ap)
{
    const int i = blockIdx.x;
    const int j = blockIdx.y;
    if (j >= i) return;
    __shared__ u64 sm[64];
    const int r = threadIdx.x;
    u64 d = Di[64 * i + r];
    sm[r] = Ap[(size_t)(64 * i + r) * NW + j];
    __syncthreads();
    u64 acc = 0;
    #pragma unroll
    for (int b = 0; b < 64; ++b)
        acc |= sm[b] & (0ull - ((d >> b) & 1ull));
    Ap[(size_t)(64 * i + r) * NW + j] = acc;
}

// ---------------------------------------------------------------------------
// K6: blocked forward-substitution closure, one block per block-column k.
//   Anc_kk = Dk;  Anc_ik = Sum_{k<=j<i} Ap'_ij * Anc_jk   (Ap' = Di-premult)
// G=4 step grouping: one pass over j serves 4 i's per colA broadcast read.
// ---------------------------------------------------------------------------
__global__ __launch_bounds__(1024) void col_kernel(
    const u64* __restrict__ Ap, const u64* __restrict__ Di,
    u64* __restrict__ Anc)
{
    __shared__ __align__(16) u64 colA[32][64];   // 16 KB
    __shared__ u64 part[16][64];                 //  8 KB
    const int t  = threadIdx.x;
    const int r  = t & 63;
    const int wv = t >> 6;
    const int k  = blockIdx.x;

    // zero strict-upper region of column k
    for (int row = t; row < 64 * k; row += 1024)
        Anc[(size_t)row * NW + k] = 0ull;

    if (t < 64) {
        u64 d = Di[64 * k + r];
        colA[0][r] = d;
        Anc[(size_t)(64 * k + r) * NW + k] = d;
    }
    __syncthreads();

    const int j0 = k + wv, j1 = k + 16 + wv;

    for (int ib = k + 1; ib < 32; ib += 4) {
        u64 m0[4], m1[4], acc[4];
        #pragma unroll
        for (int g = 0; g < 4; ++g) {
            int ig = ib + g;
            bool v = (ig < 32);
            m0[g] = (v && (j0 < ib)) ? Ap[(size_t)(64 * ig + r) * NW + j0] : 0ull;
            m1[g] = (v && (j1 < ib)) ? Ap[(size_t)(64 * ig + r) * NW + j1] : 0ull;
            acc[g] = 0ull;
        }
        u64 tm[3][3];
        #pragma unroll
        for (int s = 0; s < 3; ++s) {
            #pragma unroll
            for (int q = 0; q < 3; ++q) {
                int g = s + 1 + q;
                tm[s][q] = (g < 4 && (ib + g) < 32)
                    ? Ap[(size_t)(64 * (ib + g) + r) * NW + (ib + s)] : 0ull;
            }
        }

        // ---- main pass: j < ib, shared reads feed 4 accumulators ----
        if (j0 < ib) {
            const ulonglong2* rp = (const ulonglong2*)&colA[wv][0];
            #pragma unroll
            for (int bp = 0; bp < 32; ++bp) {
                ulonglong2 ww = rp[bp];
                #pragma unroll
                for (int g = 0; g < 4; ++g)
                    acc[g] = orsel2(acc[g], ww.x, ww.y, m0[g], 2 * bp);
            }
        }
        if (j1 < ib) {
            const ulonglong2* rp = (const ulonglong2*)&colA[16 + wv][0];
            #pragma unroll
            for (int bp = 0; bp < 32; ++bp) {
                ulonglong2 ww = rp[bp];
                #pragma unroll
                for (int g = 0; g < 4; ++g)
                    acc[g] = orsel2(acc[g], ww.x, ww.y, m1[g], 2 * bp);
            }
        }

        // ---- finalize i = ib+s, then tail slice j = ib+s for later g ----
        #pragma unroll
        for (int s = 0; s < 4; ++s) {
            const int i = ib + s;
            if (i < 32) {
                part[wv][r] = acc[s];
                __syncthreads();
                if (wv < 2) {
                    u64 red = part[0][r];
                    #pragma unroll
                    for (int p = 1; p < 16; ++p) red |= part[p][r];
                    if (wv == 0) colA[i - k][r] = red;
                    else Anc[(size_t)(64 * i + r) * NW + k] = red;
                }
                __syncthreads();
                if (s < 3 && (i + 1) < 32) {
                    const u64* rowp = colA[i - k];
                    #pragma unroll
                    for (int bi = 0; bi < 4; ++bi) {
                        int b = 4 * wv + bi;
                        u64 w = rowp[b];
                        u32 wl = (u32)w, wh = (u32)(w >> 32);
                        #pragma unroll
                        for (int q = 0; q < 3; ++q) {
                            int g = s + 1 + q;
                            if (g < 4) {
                                u32 sm2 = (u32)(0u - (u32)((tm[s][q] >> b) & 1ull));
                                u32 al = (u32)acc[g] | (wl & sm2);
                                u32 ah = (u32)(acc[g] >> 32) | (wh & sm2);
                                acc[g] = ((u64)ah << 32) | al;
                            }
                        }
                    }
                }
            }
        }
    }
}

// ---------------------------------------------------------------------------
// K7: output. he recomputed from inputs; forbidden = root[j] | ancbit | !reach_i
// ---------------------------------------------------------------------------
__global__ __launch_bounds__(256) void out_kernel(
    const float* __restrict__ edge_logits,
    const float* __restrict__ g_edge,
    const u64* __restrict__ Anc,
    const u16* __restrict__ posr,
    float* __restrict__ dag)
{
    __shared__ u64 s_anc[NW];
    __shared__ int s_pi, s_fl;
    const int i = blockIdx.x;
    const int t = threadIdx.x;
    if (t == 0) { int pr = posr[i]; s_pi = pr & 0x7FF; s_fl = pr; }
    __syncthreads();
    if (t < NW) s_anc[t] = Anc[(size_t)s_pi * NW + t];
    __syncthreads();
    const bool reach_i = (s_fl & 0x4000) != 0;
    const int j0 = t * 8;

    const float4* xe  = (const float4*)(edge_logits + (size_t)i * NN + j0);
    const float4* ge0 = (const float4*)(g_edge + (size_t)i * (2 * NN) + j0);
    const float4* ge1 = (const float4*)(g_edge + (size_t)i * (2 * NN) + NN + j0);
    float4 xa = xe[0],  xb = xe[1];
    float4 g0a = ge0[0], g0b = ge0[1];
    float4 g1a = ge1[0], g1b = ge1[1];
    float x[8]  = {xa.x, xa.y, xa.z, xa.w, xb.x, xb.y, xb.z, xb.w};
    float g0[8] = {g0a.x, g0a.y, g0a.z, g0a.w, g0b.x, g0b.y, g0b.z, g0b.w};
    float g1[8] = {g1a.x, g1a.y, g1a.z, g1a.w, g1b.x, g1b.y, g1b.z, g1b.w};

    int4 pv = *(const int4*)(posr + j0);
    int pw[4] = {pv.x, pv.y, pv.z, pv.w};

    float o[8];
    #pragma unroll
    for (int e = 0; e < 8; ++e) {
        int pr = (pw[e >> 1] >> ((e & 1) * 16)) & 0xFFFF;
        bool he = gumbel_gt(x[e], g0[e], g1[e]);
        bool root_j = (pr & 0x8000) != 0;
        int a = pr & 0x7FF;
        bool anc = ((s_anc[a >> 6] >> (a & 63)) & 1ull) != 0;
        o[e] = (reach_i && he && !root_j && !anc) ? 1.f : 0.f;
    }
    float4* outp = (float4*)(dag + (size_t)i * NN + j0);
    outp[0] = make_float4(o[0], o[1], o[2], o[3]);
    outp[1] = make_float4(o[4], o[5], o[6], o[7]);
}

// ---------------------------------------------------------------------------
extern "C" void kernel_launch(void* const* d_in, const int* in_sizes, int n_in,
                              void* d_out, int out_size, void* d_ws, size_t ws_size,
                              hipStream_t stream) {
    const float* root_logits = (const float*)d_in[0];
    const float* edge_logits = (const float*)d_in[1];
    const float* g_root      = (const float*)d_in[2];
    const float* g_edge      = (const float*)d_in[3];
    float* dag = (float*)d_out;

    u64* heBits = (u64*)d_ws;
    u64* Anc    = (u64*)d_ws;
    u16* posr    = (u16*)((char*)d_ws + (512 << 10));
    u16* porderW = (u16*)((char*)d_ws + (516 << 10));
    int* nrPtr   = (int*)((char*)d_ws + (520 << 10));
    u64* heT = (u64*)((char*)d_out + (1 << 20));
    u64* Ap  = (u64*)((char*)d_out + (1 << 20) + (512 << 10));
    u64* Di  = (u64*)((char*)d_out + (2 << 20));

    prep_kernel     <<<NN, 256, 0, stream>>>(edge_logits, g_edge, heBits);
    order_kernel    <<<1, 1024, 0, stream>>>(root_logits, g_root, heBits,
                                             posr, porderW, nrPtr);
    transpose_kernel<<<NN / 2, 64, 0, stream>>>(heBits, heT);
    apbuild_kernel  <<<NN, 256, 0, stream>>>(heT, porderW, nrPtr, Ap);
    diag_kernel     <<<NW, 64, 0, stream>>>(Ap, Di);
    ap2_kernel      <<<dim3(NW, NW), 64, 0, stream>>>(Di, Ap);
    col_kernel      <<<NW, 1024, 0, stream>>>(Ap, Di, Anc);
    out_kernel      <<<NN, 256, 0, stream>>>(edge_logits, g_edge, Anc, posr, dag);
}